// Round 9
// baseline (475.826 us; speedup 1.0000x reference)
//
#include <hip/hip_runtime.h>
#include <hip/hip_bf16.h>
#include <math.h>

#define N_NODES 50000
#define N_EDGES 800000
#define E_TOT   (N_EDGES + N_NODES)   // 850000 (with self-loops)
#define IN_CH 128
#define HID 32
#define HEADS 8
#define OUT_CH 64
#define NEG_SLOPE 0.2f
#define NBLK 196                      // ceil(50000/256)
#define M_BLK 64
#define GBLK 782                      // ceil(50000/64)
#define ABLK 12500                    // 50000/4 nodes per 256-thread block
#define A1BLK 50000                   // 6250 node-groups x 8 heads

__device__ __forceinline__ float lrelu(float x) { return x > 0.f ? x : NEG_SLOPE * x; }

__device__ __forceinline__ unsigned short f2bf(float f) {
    unsigned int u = __float_as_uint(f);
    unsigned int r = (u + 0x7FFFu + ((u >> 16) & 1u)) >> 16;   // round-nearest-even
    return (unsigned short)r;
}
__device__ __forceinline__ float bf2f(unsigned short u) {
    return __uint_as_float(((unsigned int)u) << 16);
}

// ---------------- CSR build ----------------
__global__ void hist_kernel(const int* __restrict__ ei, int* __restrict__ deg) {
    int e = blockIdx.x * blockDim.x + threadIdx.x;
    if (e >= E_TOT) return;
    int d = (e < N_EDGES) ? ei[N_EDGES + e] : (e - N_EDGES);
    atomicAdd(&deg[d], 1);
}

__global__ void scan1_kernel(const int* __restrict__ deg, int* __restrict__ off,
                             int* __restrict__ bsum) {
    __shared__ int s[256];
    int b = blockIdx.x, t = threadIdx.x, g = b * 256 + t;
    int v = (g < N_NODES) ? deg[g] : 0;
    s[t] = v;
    __syncthreads();
    for (int d = 1; d < 256; d <<= 1) {
        int o = (t >= d) ? s[t - d] : 0;
        __syncthreads();
        s[t] += o;
        __syncthreads();
    }
    if (g < N_NODES) off[g] = s[t] - v;      // exclusive, pre-block-offset
    if (t == 255) bsum[b] = s[t];
}

__global__ void scan2_kernel(int* __restrict__ bsum, int nb) {
    __shared__ int s[256];
    int t = threadIdx.x;
    int v = (t < nb) ? bsum[t] : 0;
    s[t] = v;
    __syncthreads();
    for (int d = 1; d < 256; d <<= 1) {
        int o = (t >= d) ? s[t - d] : 0;
        __syncthreads();
        s[t] += o;
        __syncthreads();
    }
    if (t < nb) bsum[t] = s[t] - v;          // exclusive block offsets
}

__global__ void scan3_kernel(int* __restrict__ off, const int* __restrict__ bsum,
                             int* __restrict__ cur) {
    int b = blockIdx.x, t = threadIdx.x, g = b * 256 + t;
    if (g < N_NODES) {
        int v = off[g] + bsum[b];
        off[g] = v;
        cur[g] = v;
    }
    if (g == 0) off[N_NODES] = E_TOT;
}

__global__ void scatter_kernel(const int* __restrict__ ei, int* __restrict__ cur,
                               int* __restrict__ ssrc) {
    int e = blockIdx.x * blockDim.x + threadIdx.x;
    if (e >= E_TOT) return;
    int s, d;
    if (e < N_EDGES) { s = ei[e]; d = ei[N_EDGES + e]; }
    else             { s = d = e - N_EDGES; }
    int pos = atomicAdd(&cur[d], 1);
    ssrc[pos] = s;
}

// ---------------- GEMM1 (tiled, 64x256 tile) + alpha epilogue ---------------
// h1 stored HEAD-MAJOR: h1s[head][node][32] bf16 (3.2 MB per head slice).
#define FMA4(accv, av, bv)                                                     \
    accv.x = fmaf(av, bv.x, accv.x); accv.y = fmaf(av, bv.y, accv.y);          \
    accv.z = fmaf(av, bv.z, accv.z); accv.w = fmaf(av, bv.w, accv.w);

__global__ __launch_bounds__(256) void gemm1_tiled(
    const float* __restrict__ x, const float* __restrict__ W1,
    const float* __restrict__ att_s, const float* __restrict__ att_d,
    unsigned short* __restrict__ h1s, float* __restrict__ as1, float* __restrict__ ad1) {
    __shared__ float As[M_BLK][IN_CH];   // 32 KB
    int t = threadIdx.x;
    int row0 = blockIdx.x * M_BLK;
#pragma unroll
    for (int i = 0; i < 8; ++i) {
        int f = t + i * 256;
        int r = f >> 5, c4 = (f & 31) * 4;
        int gr = row0 + r; if (gr >= N_NODES) gr = N_NODES - 1;
        *(float4*)&As[r][c4] = *(const float4*)&x[(size_t)gr * IN_CH + c4];
    }
    __syncthreads();
    int col0 = (t & 63) * 4;
    int rbase = (t >> 6) * 16;
    float4 acc[16];
#pragma unroll
    for (int m = 0; m < 16; ++m) acc[m] = make_float4(0.f, 0.f, 0.f, 0.f);

    for (int k = 0; k < IN_CH; k += 4) {
        float4 b0 = *(const float4*)&W1[(k + 0) * 256 + col0];
        float4 b1 = *(const float4*)&W1[(k + 1) * 256 + col0];
        float4 b2 = *(const float4*)&W1[(k + 2) * 256 + col0];
        float4 b3 = *(const float4*)&W1[(k + 3) * 256 + col0];
#pragma unroll
        for (int m = 0; m < 16; ++m) {
            float4 a = *(const float4*)&As[rbase + m][k];
            FMA4(acc[m], a.x, b0);
            FMA4(acc[m], a.y, b1);
            FMA4(acc[m], a.z, b2);
            FMA4(acc[m], a.w, b3);
        }
    }

    float4 s4 = *(const float4*)&att_s[col0];
    float4 d4 = *(const float4*)&att_d[col0];
    int head = col0 >> 5;
    int c32  = col0 & 31;
    size_t slice = (size_t)head * N_NODES * 32;
#pragma unroll
    for (int m = 0; m < 16; ++m) {
        int gr = row0 + rbase + m;
        if (gr < N_NODES) {
            ushort4 hb;
            hb.x = f2bf(acc[m].x); hb.y = f2bf(acc[m].y);
            hb.z = f2bf(acc[m].z); hb.w = f2bf(acc[m].w);
            *(ushort4*)&h1s[slice + (size_t)gr * 32 + c32] = hb;
            float p = acc[m].x * s4.x + acc[m].y * s4.y + acc[m].z * s4.z + acc[m].w * s4.w;
            float q = acc[m].x * d4.x + acc[m].y * d4.y + acc[m].z * d4.z + acc[m].w * d4.w;
            p += __shfl_xor(p, 1); p += __shfl_xor(p, 2); p += __shfl_xor(p, 4);
            q += __shfl_xor(q, 1); q += __shfl_xor(q, 2); q += __shfl_xor(q, 4);
            if ((t & 7) == 0) {
                as1[gr * HEADS + head] = p;
                ad1[gr * HEADS + head] = q;
            }
        }
    }
}

// ---------------- Aggregate layer 1: head-sliced, XCD-local -----------------
// head = blockIdx & 7  -> with round-robin block->XCD dispatch each XCD
// gathers only from its own 3.2 MB head slice (fits 4 MB per-XCD L2).
// 32 lanes per node; inline weight compute (as1/ad1 slices are L2-resident).
__global__ __launch_bounds__(256) void agg1_kernel(
    const int* __restrict__ off, const int* __restrict__ ssrc,
    const unsigned short* __restrict__ h1s, const float* __restrict__ as1,
    const float* __restrict__ ad1, const float* __restrict__ b1,
    unsigned short* __restrict__ houtb) {
    int t = threadIdx.x;
    int head = blockIdx.x & 7;
    int n = (blockIdx.x >> 3) * 8 + (t >> 5);
    int c = t & 31;
    int start = off[n], end = off[n + 1];
    float ad_h = ad1[n * HEADS + head];
    const unsigned short* tab = h1s + (size_t)head * N_NODES * 32;
    float acc0 = 0.f, den0 = 0.f, acc1 = 0.f, den1 = 0.f;
    int i = start;
    for (; i + 1 < end; i += 2) {
        int s0 = ssrc[i];
        int s1 = ssrc[i + 1];
        float w0 = __expf(lrelu(as1[s0 * HEADS + head] + ad_h));
        float w1 = __expf(lrelu(as1[s1 * HEADS + head] + ad_h));
        float v0 = bf2f(tab[(unsigned)s0 * 32 + c]);
        float v1 = bf2f(tab[(unsigned)s1 * 32 + c]);
        den0 += w0; den1 += w1;
        acc0 = fmaf(w0, v0, acc0);
        acc1 = fmaf(w1, v1, acc1);
    }
    if (i < end) {
        int s0 = ssrc[i];
        float w0 = __expf(lrelu(as1[s0 * HEADS + head] + ad_h));
        den0 += w0;
        acc0 = fmaf(w0, bf2f(tab[(unsigned)s0 * 32 + c]), acc0);
    }
    float r = __builtin_amdgcn_rcpf(den0 + den1);
    float v = fmaf(acc0 + acc1, r, b1[head * 32 + c]);
    v = v > 0.f ? v : expm1f(v);
    houtb[(unsigned)n * 256 + head * 32 + c] = f2bf(v);
}

// ---------------- GEMM2 (tiled, 64x64 tile, bf16 in) + alpha epilogue -------
__global__ __launch_bounds__(256) void gemm2_tiled(
    const unsigned short* __restrict__ hinb, const float* __restrict__ W2,
    const float* __restrict__ att_s2, const float* __restrict__ att_d2,
    unsigned short* __restrict__ h2b, float* __restrict__ as2, float* __restrict__ ad2) {
    __shared__ float As[M_BLK][256];   // 64 KB
    int t = threadIdx.x;
    int row0 = blockIdx.x * M_BLK;
#pragma unroll
    for (int i = 0; i < 16; ++i) {
        int f = t + i * 256;
        int r = f >> 6, c4 = (f & 63) * 4;
        int gr = row0 + r; if (gr >= N_NODES) gr = N_NODES - 1;
        ushort4 u = *(const ushort4*)&hinb[(size_t)gr * 256 + c4];
        float4 v = make_float4(bf2f(u.x), bf2f(u.y), bf2f(u.z), bf2f(u.w));
        *(float4*)&As[r][c4] = v;
    }
    __syncthreads();
    int col0 = (t & 31) * 2;
    int rbase = (t >> 5) * 8;
    float2 acc[8];
#pragma unroll
    for (int m = 0; m < 8; ++m) acc[m] = make_float2(0.f, 0.f);

    for (int k = 0; k < 256; k += 4) {
        float2 b0 = *(const float2*)&W2[(k + 0) * 64 + col0];
        float2 b1 = *(const float2*)&W2[(k + 1) * 64 + col0];
        float2 b2 = *(const float2*)&W2[(k + 2) * 64 + col0];
        float2 b3 = *(const float2*)&W2[(k + 3) * 64 + col0];
#pragma unroll
        for (int m = 0; m < 8; ++m) {
            float4 a = *(const float4*)&As[rbase + m][k];
            acc[m].x = fmaf(a.x, b0.x, acc[m].x); acc[m].y = fmaf(a.x, b0.y, acc[m].y);
            acc[m].x = fmaf(a.y, b1.x, acc[m].x); acc[m].y = fmaf(a.y, b1.y, acc[m].y);
            acc[m].x = fmaf(a.z, b2.x, acc[m].x); acc[m].y = fmaf(a.z, b2.y, acc[m].y);
            acc[m].x = fmaf(a.w, b3.x, acc[m].x); acc[m].y = fmaf(a.w, b3.y, acc[m].y);
        }
    }

    float2 s2v = *(const float2*)&att_s2[col0];
    float2 d2v = *(const float2*)&att_d2[col0];
#pragma unroll
    for (int m = 0; m < 8; ++m) {
        int gr = row0 + rbase + m;
        if (gr < N_NODES) {
            ushort2 hb;
            hb.x = f2bf(acc[m].x); hb.y = f2bf(acc[m].y);
            *(ushort2*)&h2b[(size_t)gr * 64 + col0] = hb;
            float p = acc[m].x * s2v.x + acc[m].y * s2v.y;
            float q = acc[m].x * d2v.x + acc[m].y * d2v.y;
            p += __shfl_xor(p, 1);  q += __shfl_xor(q, 1);
            p += __shfl_xor(p, 2);  q += __shfl_xor(q, 2);
            p += __shfl_xor(p, 4);  q += __shfl_xor(q, 4);
            p += __shfl_xor(p, 8);  q += __shfl_xor(q, 8);
            p += __shfl_xor(p, 16); q += __shfl_xor(q, 16);
            if ((t & 31) == 0) { as2[gr] = p; ad2[gr] = q; }
        }
    }
}

// ---------------- Aggregate layer 2: 1 wave/node, inline weights ------------
__global__ __launch_bounds__(256) void agg2_kernel(
    const int* __restrict__ off, const int* __restrict__ ssrc,
    const unsigned short* __restrict__ h2b, const float* __restrict__ as2,
    const float* __restrict__ ad2, const float* __restrict__ b2,
    float* __restrict__ out) {
    int t = threadIdx.x;
    int lane = t & 63;
    int n = blockIdx.x * 4 + (t >> 6);
    int start = off[n], end = off[n + 1];
    float adv = ad2[n];
    float acc0 = 0.f, den0 = 0.f, acc1 = 0.f, den1 = 0.f;
    int i = start;
    for (; i + 1 < end; i += 2) {
        int s0 = ssrc[i];
        int s1 = ssrc[i + 1];
        float w0 = __expf(lrelu(as2[s0] + adv));
        float w1 = __expf(lrelu(as2[s1] + adv));
        float v0 = bf2f(h2b[(unsigned)s0 * 64 + lane]);
        float v1 = bf2f(h2b[(unsigned)s1 * 64 + lane]);
        den0 += w0; den1 += w1;
        acc0 = fmaf(w0, v0, acc0);
        acc1 = fmaf(w1, v1, acc1);
    }
    if (i < end) {
        int s0 = ssrc[i];
        float w0 = __expf(lrelu(as2[s0] + adv));
        den0 += w0;
        acc0 = fmaf(w0, bf2f(h2b[(unsigned)s0 * 64 + lane]), acc0);
    }
    float r = __builtin_amdgcn_rcpf(den0 + den1);
    out[(unsigned)n * 64 + lane] = fmaf(acc0 + acc1, r, b2[lane]);
}

extern "C" void kernel_launch(void* const* d_in, const int* in_sizes, int n_in,
                              void* d_out, int out_size, void* d_ws, size_t ws_size,
                              hipStream_t stream) {
    const float* x    = (const float*)d_in[0];
    const int*   ei   = (const int*)d_in[1];
    const float* W1   = (const float*)d_in[2];
    const float* ats1 = (const float*)d_in[3];
    const float* atd1 = (const float*)d_in[4];
    const float* b1   = (const float*)d_in[5];
    const float* W2   = (const float*)d_in[6];
    const float* ats2 = (const float*)d_in[7];
    const float* atd2 = (const float*)d_in[8];
    const float* b2   = (const float*)d_in[9];
    float* out = (float*)d_out;

    char* ws = (char*)d_ws;
    size_t o = 0;
    auto alloc = [&](size_t bytes) { size_t r = o; o = (o + bytes + 255) & ~255UL; return r; };
    unsigned short* h1s   = (unsigned short*)(ws + alloc((size_t)N_NODES * 256 * 2));
    unsigned short* h2inb = (unsigned short*)(ws + alloc((size_t)N_NODES * 256 * 2));
    unsigned short* h2b   = (unsigned short*)(ws + alloc((size_t)N_NODES * 64 * 2));
    float* as1  = (float*)(ws + alloc((size_t)N_NODES * HEADS * 4));
    float* ad1  = (float*)(ws + alloc((size_t)N_NODES * HEADS * 4));
    float* as2  = (float*)(ws + alloc((size_t)N_NODES * 4));
    float* ad2  = (float*)(ws + alloc((size_t)N_NODES * 4));
    int*   deg  = (int*)(ws + alloc((size_t)N_NODES * 4));
    int*   off  = (int*)(ws + alloc((size_t)(N_NODES + 1) * 4));
    int*   cur  = (int*)(ws + alloc((size_t)N_NODES * 4));
    int*   bsum = (int*)(ws + alloc(256 * 4));
    int*   ssrc = (int*)(ws + alloc((size_t)E_TOT * 4));

    (void)hipMemsetAsync(deg, 0, (size_t)N_NODES * 4, stream);
    int eblk = (E_TOT + 255) / 256;
    hist_kernel<<<eblk, 256, 0, stream>>>(ei, deg);
    scan1_kernel<<<NBLK, 256, 0, stream>>>(deg, off, bsum);
    scan2_kernel<<<1, 256, 0, stream>>>(bsum, NBLK);
    scan3_kernel<<<NBLK, 256, 0, stream>>>(off, bsum, cur);
    scatter_kernel<<<eblk, 256, 0, stream>>>(ei, cur, ssrc);

    gemm1_tiled<<<GBLK, 256, 0, stream>>>(x, W1, ats1, atd1, h1s, as1, ad1);
    agg1_kernel<<<A1BLK, 256, 0, stream>>>(off, ssrc, h1s, as1, ad1, b1, h2inb);

    gemm2_tiled<<<GBLK, 256, 0, stream>>>(h2inb, W2, ats2, atd2, h2b, as2, ad2);
    agg2_kernel<<<ABLK, 256, 0, stream>>>(off, ssrc, h2b, as2, ad2, b2, out);
}

// Round 10
// 313.847 us; speedup vs baseline: 1.5161x; 1.5161x over previous
//
#include <hip/hip_runtime.h>
#include <hip/hip_bf16.h>
#include <math.h>

#define N_NODES 50000
#define N_EDGES 800000
#define E_TOT   (N_EDGES + N_NODES)   // 850000 (with self-loops)
#define IN_CH 128
#define HID 32
#define HEADS 8
#define OUT_CH 64
#define NEG_SLOPE 0.2f
#define NBLK 196                      // ceil(50000/256)
#define M_BLK 64
#define GBLK 782                      // ceil(50000/64)
#define ABLK 12500                    // 50000/4 nodes per 256-thread block
#define LOG2E 1.4426950408889634f

__device__ __forceinline__ float lrelu(float x) { return x > 0.f ? x : NEG_SLOPE * x; }
// exp(lrelu(z)) = exp2(max(z*L, z*0.2L))  (branchless; valid since L>0)
__device__ __forceinline__ float explrelu(float z) {
    return exp2f(fmaxf(z * LOG2E, z * (NEG_SLOPE * LOG2E)));
}

__device__ __forceinline__ unsigned short f2bf(float f) {
    unsigned int u = __float_as_uint(f);
    unsigned int r = (u + 0x7FFFu + ((u >> 16) & 1u)) >> 16;   // round-nearest-even
    return (unsigned short)r;
}
__device__ __forceinline__ float bf2f(unsigned short u) {
    return __uint_as_float(((unsigned int)u) << 16);
}
__device__ __forceinline__ float bflo(unsigned int u) {       // low ushort -> float
    return __uint_as_float(u << 16);
}
__device__ __forceinline__ float bfhi(unsigned int u) {       // high ushort -> float
    return __uint_as_float(u & 0xFFFF0000u);
}

// ---------------- CSR build ----------------
__global__ void hist_kernel(const int* __restrict__ ei, int* __restrict__ deg) {
    int e = blockIdx.x * blockDim.x + threadIdx.x;
    if (e >= E_TOT) return;
    int d = (e < N_EDGES) ? ei[N_EDGES + e] : (e - N_EDGES);
    atomicAdd(&deg[d], 1);
}

__global__ void scan1_kernel(const int* __restrict__ deg, int* __restrict__ off,
                             int* __restrict__ bsum) {
    __shared__ int s[256];
    int b = blockIdx.x, t = threadIdx.x, g = b * 256 + t;
    int v = (g < N_NODES) ? deg[g] : 0;
    s[t] = v;
    __syncthreads();
    for (int d = 1; d < 256; d <<= 1) {
        int o = (t >= d) ? s[t - d] : 0;
        __syncthreads();
        s[t] += o;
        __syncthreads();
    }
    if (g < N_NODES) off[g] = s[t] - v;
    if (t == 255) bsum[b] = s[t];
}

__global__ void scan2_kernel(int* __restrict__ bsum, int nb) {
    __shared__ int s[256];
    int t = threadIdx.x;
    int v = (t < nb) ? bsum[t] : 0;
    s[t] = v;
    __syncthreads();
    for (int d = 1; d < 256; d <<= 1) {
        int o = (t >= d) ? s[t - d] : 0;
        __syncthreads();
        s[t] += o;
        __syncthreads();
    }
    if (t < nb) bsum[t] = s[t] - v;
}

__global__ void scan3_kernel(int* __restrict__ off, const int* __restrict__ bsum,
                             int* __restrict__ cur) {
    int b = blockIdx.x, t = threadIdx.x, g = b * 256 + t;
    if (g < N_NODES) {
        int v = off[g] + bsum[b];
        off[g] = v;
        cur[g] = v;
    }
    if (g == 0) off[N_NODES] = E_TOT;
}

__global__ void scatter_kernel(const int* __restrict__ ei, int* __restrict__ cur,
                               int* __restrict__ ssrc) {
    int e = blockIdx.x * blockDim.x + threadIdx.x;
    if (e >= E_TOT) return;
    int s, d;
    if (e < N_EDGES) { s = ei[e]; d = ei[N_EDGES + e]; }
    else             { s = d = e - N_EDGES; }
    int pos = atomicAdd(&cur[d], 1);
    ssrc[pos] = s;
}

// ---------------- GEMM1 (tiled, 64x256 tile) + alpha epilogue, bf16 h1 out ---
#define FMA4(accv, av, bv)                                                     \
    accv.x = fmaf(av, bv.x, accv.x); accv.y = fmaf(av, bv.y, accv.y);          \
    accv.z = fmaf(av, bv.z, accv.z); accv.w = fmaf(av, bv.w, accv.w);

__global__ __launch_bounds__(256) void gemm1_tiled(
    const float* __restrict__ x, const float* __restrict__ W1,
    const float* __restrict__ att_s, const float* __restrict__ att_d,
    unsigned short* __restrict__ h1b, float* __restrict__ as1, float* __restrict__ ad1) {
    __shared__ float As[M_BLK][IN_CH];   // 32 KB
    int t = threadIdx.x;
    int row0 = blockIdx.x * M_BLK;
#pragma unroll
    for (int i = 0; i < 8; ++i) {
        int f = t + i * 256;
        int r = f >> 5, c4 = (f & 31) * 4;
        int gr = row0 + r; if (gr >= N_NODES) gr = N_NODES - 1;
        *(float4*)&As[r][c4] = *(const float4*)&x[(size_t)gr * IN_CH + c4];
    }
    __syncthreads();
    int col0 = (t & 63) * 4;
    int rbase = (t >> 6) * 16;
    float4 acc[16];
#pragma unroll
    for (int m = 0; m < 16; ++m) acc[m] = make_float4(0.f, 0.f, 0.f, 0.f);

    for (int k = 0; k < IN_CH; k += 4) {
        float4 b0 = *(const float4*)&W1[(k + 0) * 256 + col0];
        float4 b1 = *(const float4*)&W1[(k + 1) * 256 + col0];
        float4 b2 = *(const float4*)&W1[(k + 2) * 256 + col0];
        float4 b3 = *(const float4*)&W1[(k + 3) * 256 + col0];
#pragma unroll
        for (int m = 0; m < 16; ++m) {
            float4 a = *(const float4*)&As[rbase + m][k];
            FMA4(acc[m], a.x, b0);
            FMA4(acc[m], a.y, b1);
            FMA4(acc[m], a.z, b2);
            FMA4(acc[m], a.w, b3);
        }
    }

    float4 s4 = *(const float4*)&att_s[col0];
    float4 d4 = *(const float4*)&att_d[col0];
    int head = col0 >> 5;
#pragma unroll
    for (int m = 0; m < 16; ++m) {
        int gr = row0 + rbase + m;
        if (gr < N_NODES) {
            ushort4 hb;
            hb.x = f2bf(acc[m].x); hb.y = f2bf(acc[m].y);
            hb.z = f2bf(acc[m].z); hb.w = f2bf(acc[m].w);
            *(ushort4*)&h1b[(size_t)gr * 256 + col0] = hb;
            float p = acc[m].x * s4.x + acc[m].y * s4.y + acc[m].z * s4.z + acc[m].w * s4.w;
            float q = acc[m].x * d4.x + acc[m].y * d4.y + acc[m].z * d4.z + acc[m].w * d4.w;
            p += __shfl_xor(p, 1); p += __shfl_xor(p, 2); p += __shfl_xor(p, 4);
            q += __shfl_xor(q, 1); q += __shfl_xor(q, 2); q += __shfl_xor(q, 4);
            if ((t & 7) == 0) {
                as1[gr * HEADS + head] = p;
                ad1[gr * HEADS + head] = q;
            }
        }
    }
}

// ---------------- Aggregate layer 1: 1 wave/node, 8-edge batched weights ----
// lane l: channels [l*4,l*4+4), head h = l>>3.
// Batch of 8 edges: lanes 0..63 compute all 64 (edge,head) weights at once
// (one as1 gather + one exp chain), then 2 shfl/edge redistribute.
__global__ __launch_bounds__(256) void agg1_kernel(
    const int* __restrict__ off, const int* __restrict__ ssrc,
    const unsigned short* __restrict__ h1b, const float* __restrict__ as1,
    const float* __restrict__ ad1, const float* __restrict__ b1,
    unsigned short* __restrict__ houtb) {
    int t = threadIdx.x;
    int lane = t & 63;
    int n = blockIdx.x * 4 + (t >> 6);
    int h = lane >> 3;
    int e8 = lane & 7;
    int c0 = lane * 4;
    int start = off[n], end = off[n + 1];
    float ad_w = ad1[n * HEADS + e8];   // for weight phase (lane computes head e8)
    float ad_h = ad1[n * HEADS + h];    // for tail phase (lane consumes head h)
    float4 acc = make_float4(0.f, 0.f, 0.f, 0.f);
    float den = 0.f;
    int i = start;
    for (; i + 8 <= end; i += 8) {
        int sv = ssrc[i + e8];                    // lanes 0-7 hold the 8 srcs (replicated)
        int se = __shfl(sv, lane >> 3);           // src of edge (lane>>3)
        float z = as1[se * HEADS + e8] + ad_w;    // alpha(edge l>>3, head l&7)
        float wv = explrelu(z);                   // 64 weights in one chain
#pragma unroll
        for (int j = 0; j < 8; ++j) {
            float wj = __shfl(wv, j * 8 + h);     // w(edge j, my head)
            int   sj = __shfl(sv, j);             // src of edge j
            uint2 u = *(const uint2*)&h1b[(unsigned)sj * 256 + c0];
            den += wj;
            acc.x = fmaf(wj, bflo(u.x), acc.x);
            acc.y = fmaf(wj, bfhi(u.x), acc.y);
            acc.z = fmaf(wj, bflo(u.y), acc.z);
            acc.w = fmaf(wj, bfhi(u.y), acc.w);
        }
    }
    for (; i < end; ++i) {                        // tail (< 8 edges)
        int s0 = ssrc[i];
        float w0 = explrelu(as1[s0 * HEADS + h] + ad_h);
        uint2 u = *(const uint2*)&h1b[(unsigned)s0 * 256 + c0];
        den += w0;
        acc.x = fmaf(w0, bflo(u.x), acc.x);
        acc.y = fmaf(w0, bfhi(u.x), acc.y);
        acc.z = fmaf(w0, bflo(u.y), acc.z);
        acc.w = fmaf(w0, bfhi(u.y), acc.w);
    }
    float r = __builtin_amdgcn_rcpf(den);
    float4 bv = *(const float4*)&b1[c0];
    float vx = fmaf(acc.x, r, bv.x);
    float vy = fmaf(acc.y, r, bv.y);
    float vz = fmaf(acc.z, r, bv.z);
    float vw = fmaf(acc.w, r, bv.w);
    vx = vx > 0.f ? vx : expm1f(vx);
    vy = vy > 0.f ? vy : expm1f(vy);
    vz = vz > 0.f ? vz : expm1f(vz);
    vw = vw > 0.f ? vw : expm1f(vw);
    ushort4 ob;
    ob.x = f2bf(vx); ob.y = f2bf(vy); ob.z = f2bf(vz); ob.w = f2bf(vw);
    *(ushort4*)&houtb[(unsigned)n * 256 + c0] = ob;
}

// ---------------- GEMM2 (tiled, 64x64 tile, bf16 in) + alpha epilogue -------
__global__ __launch_bounds__(256) void gemm2_tiled(
    const unsigned short* __restrict__ hinb, const float* __restrict__ W2,
    const float* __restrict__ att_s2, const float* __restrict__ att_d2,
    unsigned short* __restrict__ h2b, float* __restrict__ as2, float* __restrict__ ad2) {
    __shared__ float As[M_BLK][256];   // 64 KB
    int t = threadIdx.x;
    int row0 = blockIdx.x * M_BLK;
#pragma unroll
    for (int i = 0; i < 16; ++i) {
        int f = t + i * 256;
        int r = f >> 6, c4 = (f & 63) * 4;
        int gr = row0 + r; if (gr >= N_NODES) gr = N_NODES - 1;
        ushort4 u = *(const ushort4*)&hinb[(size_t)gr * 256 + c4];
        float4 v = make_float4(bf2f(u.x), bf2f(u.y), bf2f(u.z), bf2f(u.w));
        *(float4*)&As[r][c4] = v;
    }
    __syncthreads();
    int col0 = (t & 31) * 2;
    int rbase = (t >> 5) * 8;
    float2 acc[8];
#pragma unroll
    for (int m = 0; m < 8; ++m) acc[m] = make_float2(0.f, 0.f);

    for (int k = 0; k < 256; k += 4) {
        float2 b0 = *(const float2*)&W2[(k + 0) * 64 + col0];
        float2 b1 = *(const float2*)&W2[(k + 1) * 64 + col0];
        float2 b2 = *(const float2*)&W2[(k + 2) * 64 + col0];
        float2 b3 = *(const float2*)&W2[(k + 3) * 64 + col0];
#pragma unroll
        for (int m = 0; m < 8; ++m) {
            float4 a = *(const float4*)&As[rbase + m][k];
            acc[m].x = fmaf(a.x, b0.x, acc[m].x); acc[m].y = fmaf(a.x, b0.y, acc[m].y);
            acc[m].x = fmaf(a.y, b1.x, acc[m].x); acc[m].y = fmaf(a.y, b1.y, acc[m].y);
            acc[m].x = fmaf(a.z, b2.x, acc[m].x); acc[m].y = fmaf(a.z, b2.y, acc[m].y);
            acc[m].x = fmaf(a.w, b3.x, acc[m].x); acc[m].y = fmaf(a.w, b3.y, acc[m].y);
        }
    }

    float2 s2v = *(const float2*)&att_s2[col0];
    float2 d2v = *(const float2*)&att_d2[col0];
#pragma unroll
    for (int m = 0; m < 8; ++m) {
        int gr = row0 + rbase + m;
        if (gr < N_NODES) {
            ushort2 hb;
            hb.x = f2bf(acc[m].x); hb.y = f2bf(acc[m].y);
            *(ushort2*)&h2b[(size_t)gr * 64 + col0] = hb;
            float p = acc[m].x * s2v.x + acc[m].y * s2v.y;
            float q = acc[m].x * d2v.x + acc[m].y * d2v.y;
            p += __shfl_xor(p, 1);  q += __shfl_xor(q, 1);
            p += __shfl_xor(p, 2);  q += __shfl_xor(q, 2);
            p += __shfl_xor(p, 4);  q += __shfl_xor(q, 4);
            p += __shfl_xor(p, 8);  q += __shfl_xor(q, 8);
            p += __shfl_xor(p, 16); q += __shfl_xor(q, 16);
            if ((t & 31) == 0) { as2[gr] = p; ad2[gr] = q; }
        }
    }
}

// ---------------- Aggregate layer 2: 1 wave/node, 8-edge batched weights ----
__global__ __launch_bounds__(256) void agg2_kernel(
    const int* __restrict__ off, const int* __restrict__ ssrc,
    const unsigned short* __restrict__ h2b, const float* __restrict__ as2,
    const float* __restrict__ ad2, const float* __restrict__ b2,
    float* __restrict__ out) {
    int t = threadIdx.x;
    int lane = t & 63;
    int e8 = lane & 7;
    int n = blockIdx.x * 4 + (t >> 6);
    int start = off[n], end = off[n + 1];
    float adv = ad2[n];
    float acc = 0.f, den = 0.f;
    int i = start;
    for (; i + 8 <= end; i += 8) {
        int sv = ssrc[i + e8];                 // lanes (l&7) hold the 8 srcs
        float wv = explrelu(as2[sv] + adv);    // 8 weights (replicated across groups)
#pragma unroll
        for (int j = 0; j < 8; ++j) {
            float wj = __shfl(wv, j);
            int   sj = __shfl(sv, j);
            float v = bf2f(h2b[(unsigned)sj * 64 + lane]);
            den += wj;
            acc = fmaf(wj, v, acc);
        }
    }
    for (; i < end; ++i) {
        int s0 = ssrc[i];
        float w0 = explrelu(as2[s0] + adv);
        den += w0;
        acc = fmaf(w0, bf2f(h2b[(unsigned)s0 * 64 + lane]), acc);
    }
    float r = __builtin_amdgcn_rcpf(den);
    out[(unsigned)n * 64 + lane] = fmaf(acc, r, b2[lane]);
}

extern "C" void kernel_launch(void* const* d_in, const int* in_sizes, int n_in,
                              void* d_out, int out_size, void* d_ws, size_t ws_size,
                              hipStream_t stream) {
    const float* x    = (const float*)d_in[0];
    const int*   ei   = (const int*)d_in[1];
    const float* W1   = (const float*)d_in[2];
    const float* ats1 = (const float*)d_in[3];
    const float* atd1 = (const float*)d_in[4];
    const float* b1   = (const float*)d_in[5];
    const float* W2   = (const float*)d_in[6];
    const float* ats2 = (const float*)d_in[7];
    const float* atd2 = (const float*)d_in[8];
    const float* b2   = (const float*)d_in[9];
    float* out = (float*)d_out;

    char* ws = (char*)d_ws;
    size_t o = 0;
    auto alloc = [&](size_t bytes) { size_t r = o; o = (o + bytes + 255) & ~255UL; return r; };
    unsigned short* h1b   = (unsigned short*)(ws + alloc((size_t)N_NODES * 256 * 2));
    unsigned short* h2inb = (unsigned short*)(ws + alloc((size_t)N_NODES * 256 * 2));
    unsigned short* h2b   = (unsigned short*)(ws + alloc((size_t)N_NODES * 64 * 2));
    float* as1  = (float*)(ws + alloc((size_t)N_NODES * HEADS * 4));
    float* ad1  = (float*)(ws + alloc((size_t)N_NODES * HEADS * 4));
    float* as2  = (float*)(ws + alloc((size_t)N_NODES * 4));
    float* ad2  = (float*)(ws + alloc((size_t)N_NODES * 4));
    int*   deg  = (int*)(ws + alloc((size_t)N_NODES * 4));
    int*   off  = (int*)(ws + alloc((size_t)(N_NODES + 1) * 4));
    int*   cur  = (int*)(ws + alloc((size_t)N_NODES * 4));
    int*   bsum = (int*)(ws + alloc(256 * 4));
    int*   ssrc = (int*)(ws + alloc((size_t)E_TOT * 4));

    (void)hipMemsetAsync(deg, 0, (size_t)N_NODES * 4, stream);
    int eblk = (E_TOT + 255) / 256;
    hist_kernel<<<eblk, 256, 0, stream>>>(ei, deg);
    scan1_kernel<<<NBLK, 256, 0, stream>>>(deg, off, bsum);
    scan2_kernel<<<1, 256, 0, stream>>>(bsum, NBLK);
    scan3_kernel<<<NBLK, 256, 0, stream>>>(off, bsum, cur);
    scatter_kernel<<<eblk, 256, 0, stream>>>(ei, cur, ssrc);

    gemm1_tiled<<<GBLK, 256, 0, stream>>>(x, W1, ats1, atd1, h1b, as1, ad1);
    agg1_kernel<<<ABLK, 256, 0, stream>>>(off, ssrc, h1b, as1, ad1, b1, h2inb);

    gemm2_tiled<<<GBLK, 256, 0, stream>>>(h2inb, W2, ats2, atd2, h2b, as2, ad2);
    agg2_kernel<<<ABLK, 256, 0, stream>>>(off, ssrc, h2b, as2, ad2, b2, out);
}